// Round 2
// baseline (436.103 us; speedup 1.0000x reference)
//
#include <hip/hip_runtime.h>
#include <math.h>

#define NT 128        // trees
#define NB 1024       // batch
#define ND 784        // feature dim
#define NK 200        // top-k
#define ND4 196       // ND / 4
#define TND4 (NT * ND4)     // 25088 vfloat4 per batch row
#define HALF4 (TND4 / 2)    // 12544 = 64 trees worth of vfloat4

typedef float vfloat4 __attribute__((ext_vector_type(4)));

// ---------------------------------------------------------------------------
// Kernel 1 (unchanged): per-tree top-K, register-resident radix select.
// Block per tree, 256 threads; each thread owns 4 keys in VGPRs. One barrier
// per bit via [32][4] slot array. Tie-pick (lowest index first) via
// ballot+popcount ordered rank. sigmoid monotonic => top-k on raw mask bits.
// ---------------------------------------------------------------------------
__global__ __launch_bounds__(256) void topk_attention_kernel(
    const float* __restrict__ mask, float* __restrict__ att_out)
{
    __shared__ int wsum[32][4];
    __shared__ int wtie[4][4];

    const int t    = blockIdx.x;
    const int tid  = threadIdx.x;
    const int wave = tid >> 6;
    const int lane = tid & 63;

    unsigned int key[4];
    float        val[4];
    #pragma unroll
    for (int j = 0; j < 4; ++j) {
        const int d = tid + j * 256;
        if (d < ND) {
            const float f = mask[t * ND + d];
            const unsigned int b = __float_as_uint(f);
            key[j] = ((int)b < 0) ? ~b : (b | 0x80000000u);  // order-preserving
            val[j] = 1.0f / (1.0f + expf(-f));
        } else { key[j] = 0u; val[j] = 0.0f; }               // pad: never selected
    }

    unsigned int p = 0;
    int need = NK;
    for (int bit = 31; bit >= 0; --bit) {
        const unsigned int test = (p >> bit) | 1u;
        int c = 0;
        #pragma unroll
        for (int j = 0; j < 4; ++j) c += ((key[j] >> bit) == test) ? 1 : 0;
        #pragma unroll
        for (int off = 32; off > 0; off >>= 1) c += __shfl_down(c, off);
        if (lane == 0) wsum[bit][wave] = c;
        __syncthreads();
        const int tot = wsum[bit][0] + wsum[bit][1] + wsum[bit][2] + wsum[bit][3];
        if (tot >= need) p |= (1u << bit);
        else             need -= tot;
    }

    // ordered tie ranks: ascending d == ascending (j, wave, lane)
    int rankw[4];
    #pragma unroll
    for (int j = 0; j < 4; ++j) {
        const bool tie = (key[j] == p);
        const unsigned long long m = __ballot(tie);
        rankw[j] = __popcll(m & ((1ull << lane) - 1ull));
        if (lane == 0) wtie[j][wave] = __popcll(m);
    }
    __syncthreads();
    int jbase[4];
    {
        int pre = 0;
        #pragma unroll
        for (int j = 0; j < 4; ++j) {
            jbase[j] = pre;
            pre += wtie[j][0] + wtie[j][1] + wtie[j][2] + wtie[j][3];
        }
    }

    #pragma unroll
    for (int j = 0; j < 4; ++j) {
        const int d = tid + j * 256;
        if (d < ND) {
            bool keep = key[j] > p;
            if (key[j] == p) {
                int off = jbase[j] + rankw[j];
                for (int w = 0; w < 4; ++w) if (w < wave) off += wtie[j][w];
                keep = off < need;
            }
            att_out[t * ND + d] = keep ? val[j] : 0.0f;
        }
    }
}

// ---------------------------------------------------------------------------
// Kernel 2 v5: fill-shaped. The harness's poison fill hits 6.3 TB/s
// (10.3 B/cyc/CU) on this exact output buffer with tiny 256-thread blocks
// and plain stores; v3/v4's monolithic pipelined blocks sat at 5.6 B/cyc/CU
// and cutting their read traffic 4x changed nothing (reads are free).
// So: mimic the fill. 49x1024 blocks of 256 threads, no LDS, no barriers,
// no unroll pipeline, plain (cached) stores. Each thread: one x4 load
// (L2-hot, 3 MB), two att4 loads (L2/LLC-hot, 401 KB), two independent
// muls + stores. k and k+12544 share d4 (12544 = 64*196), so one magic-div
// serves both halves.
// ---------------------------------------------------------------------------
__global__ __launch_bounds__(256) void bcast_mul_kernel(
    const vfloat4* __restrict__ x4, const vfloat4* __restrict__ att4,
    vfloat4* __restrict__ out4)
{
    const int b = blockIdx.y;
    const int k = blockIdx.x * 256 + threadIdx.x;        // 0..12543
    const unsigned int t = (unsigned int)k / 196u;       // tree 0..63
    const int d4 = k - (int)(t * 196u);

    const vfloat4 xs = x4[b * ND4 + d4];
    const vfloat4 a0 = att4[k];
    const vfloat4 a1 = att4[k + HALF4];

    vfloat4* __restrict__ ob = out4 + (size_t)b * TND4 + k;
    ob[0]     = a0 * xs;
    ob[HALF4] = a1 * xs;
}

extern "C" void kernel_launch(void* const* d_in, const int* in_sizes, int n_in,
                              void* d_out, int out_size, void* d_ws, size_t ws_size,
                              hipStream_t stream)
{
    (void)in_sizes; (void)n_in; (void)out_size; (void)d_ws; (void)ws_size;
    const float* x    = (const float*)d_in[0];
    const float* mask = (const float*)d_in[1];
    float* out = (float*)d_out;
    float* att = out + (size_t)NB * NT * ND;   // attention output region

    topk_attention_kernel<<<NT, 256, 0, stream>>>(mask, att);
    bcast_mul_kernel<<<dim3(HALF4 / 256, NB), 256, 0, stream>>>(
        (const vfloat4*)x, (const vfloat4*)att, (vfloat4*)out);
}

// Round 3
// 422.141 us; speedup vs baseline: 1.0331x; 1.0331x over previous
//
#include <hip/hip_runtime.h>
#include <math.h>

#define NT 128        // trees
#define NB 1024       // batch
#define ND 784        // feature dim
#define NK 200        // top-k
#define ND4 196       // ND / 4
#define UB 7          // bcast pipeline batch (98 iters = 14 batches of 7)

typedef float vfloat4 __attribute__((ext_vector_type(4)));

// ---------------------------------------------------------------------------
// Kernel 1 (unchanged): per-tree top-K, register-resident radix select.
// ---------------------------------------------------------------------------
__global__ __launch_bounds__(256) void topk_attention_kernel(
    const float* __restrict__ mask, float* __restrict__ att_out)
{
    __shared__ int wsum[32][4];
    __shared__ int wtie[4][4];

    const int t    = blockIdx.x;
    const int tid  = threadIdx.x;
    const int wave = tid >> 6;
    const int lane = tid & 63;

    unsigned int key[4];
    float        val[4];
    #pragma unroll
    for (int j = 0; j < 4; ++j) {
        const int d = tid + j * 256;
        if (d < ND) {
            const float f = mask[t * ND + d];
            const unsigned int b = __float_as_uint(f);
            key[j] = ((int)b < 0) ? ~b : (b | 0x80000000u);  // order-preserving
            val[j] = 1.0f / (1.0f + expf(-f));
        } else { key[j] = 0u; val[j] = 0.0f; }               // pad: never selected
    }

    unsigned int p = 0;
    int need = NK;
    for (int bit = 31; bit >= 0; --bit) {
        const unsigned int test = (p >> bit) | 1u;
        int c = 0;
        #pragma unroll
        for (int j = 0; j < 4; ++j) c += ((key[j] >> bit) == test) ? 1 : 0;
        #pragma unroll
        for (int off = 32; off > 0; off >>= 1) c += __shfl_down(c, off);
        if (lane == 0) wsum[bit][wave] = c;
        __syncthreads();
        const int tot = wsum[bit][0] + wsum[bit][1] + wsum[bit][2] + wsum[bit][3];
        if (tot >= need) p |= (1u << bit);
        else             need -= tot;
    }

    // ordered tie ranks: ascending d == ascending (j, wave, lane)
    int rankw[4];
    #pragma unroll
    for (int j = 0; j < 4; ++j) {
        const bool tie = (key[j] == p);
        const unsigned long long m = __ballot(tie);
        rankw[j] = __popcll(m & ((1ull << lane) - 1ull));
        if (lane == 0) wtie[j][wave] = __popcll(m);
    }
    __syncthreads();
    int jbase[4];
    {
        int pre = 0;
        #pragma unroll
        for (int j = 0; j < 4; ++j) {
            jbase[j] = pre;
            pre += wtie[j][0] + wtie[j][1] + wtie[j][2] + wtie[j][3];
        }
    }

    #pragma unroll
    for (int j = 0; j < 4; ++j) {
        const int d = tid + j * 256;
        if (d < ND) {
            bool keep = key[j] > p;
            if (key[j] == p) {
                int off = jbase[j] + rankw[j];
                for (int w = 0; w < 4; ++w) if (w < wave) off += wtie[j][w];
                keep = off < need;
            }
            att_out[t * ND + d] = keep ? val[j] : 0.0f;
        }
    }
}

// ---------------------------------------------------------------------------
// Streaming store: full cache-policy bits (sc0 sc1 nt) — the gfx950
// equivalent of the fill path's no-allocate, no-RFO write. A/B vs v3
// (identical structure): __builtin_nontemporal_store sets only nt and
// left us at 2.1x write-roofline; theory is the store-miss L2
// allocate/fetch is the hidden ~411 MB of HBM reads.
// ---------------------------------------------------------------------------
__device__ __forceinline__ void store_stream(vfloat4* p, vfloat4 v)
{
    asm volatile("global_store_dwordx4 %0, %1, off sc0 sc1 nt"
                 : : "v"(p), "v"(v) : "memory");
}

// ---------------------------------------------------------------------------
// Kernel 2 v6: identical structure to v3 (block per batch row, x row in LDS,
// att prefetched in register batches of UB=7 with loads issued before the
// previous batch's stores). ONLY change: stores go through store_stream.
// ---------------------------------------------------------------------------
__global__ __launch_bounds__(256) void bcast_mul_kernel(
    const vfloat4* __restrict__ x4, const vfloat4* __restrict__ att4,
    vfloat4* __restrict__ out4)
{
    __shared__ vfloat4 sx[ND4];
    const int b   = blockIdx.x;
    const int tid = threadIdx.x;
    if (tid < ND4) sx[tid] = x4[b * ND4 + tid];
    __syncthreads();

    vfloat4* __restrict__ outb = out4 + (size_t)b * (NT * ND4);

    vfloat4 cur[UB];
    #pragma unroll
    for (int u = 0; u < UB; ++u) cur[u] = att4[tid + u * 256];

    int d4 = (tid >= ND4) ? tid - ND4 : tid;   // (tid + 256k) mod 196, k=0

    for (int nb = 0; nb < 13; ++nb) {          // batches 0..12 prefetch next
        vfloat4 nxt[UB];
        const int kb = nb * UB;
        #pragma unroll
        for (int u = 0; u < UB; ++u) nxt[u] = att4[tid + (kb + UB + u) * 256];
        #pragma unroll
        for (int u = 0; u < UB; ++u) {
            const vfloat4 o = cur[u] * sx[d4];
            store_stream(&outb[tid + (kb + u) * 256], o);
            d4 += 60; if (d4 >= ND4) d4 -= ND4;   // (i+256) mod 196
        }
        #pragma unroll
        for (int u = 0; u < UB; ++u) cur[u] = nxt[u];
    }
    // final batch (13): stores only
    #pragma unroll
    for (int u = 0; u < UB; ++u) {
        const vfloat4 o = cur[u] * sx[d4];
        store_stream(&outb[tid + (13 * UB + u) * 256], o);
        d4 += 60; if (d4 >= ND4) d4 -= ND4;
    }
}

extern "C" void kernel_launch(void* const* d_in, const int* in_sizes, int n_in,
                              void* d_out, int out_size, void* d_ws, size_t ws_size,
                              hipStream_t stream)
{
    (void)in_sizes; (void)n_in; (void)out_size; (void)d_ws; (void)ws_size;
    const float* x    = (const float*)d_in[0];
    const float* mask = (const float*)d_in[1];
    float* out = (float*)d_out;
    float* att = out + (size_t)NB * NT * ND;   // attention output region

    topk_attention_kernel<<<NT, 256, 0, stream>>>(mask, att);
    bcast_mul_kernel<<<NB, 256, 0, stream>>>(
        (const vfloat4*)x, (const vfloat4*)att, (vfloat4*)out);
}